// Round 1
// baseline (157.180 us; speedup 1.0000x reference)
//
#include <hip/hip_runtime.h>

#define N_AG   4608
#define NPO    1536
#define D_DIM  256
#define H_DIM  512
#define GRID_SZ 256

// ---------------------------------------------------------------------------
// Tiled fp32 GEMM with per-org weights: out[m][n] = act(sum_k S[m][k]*W[org(m)][k][n] + bias[org][n])
// Tile 64x64, BK=16, 256 threads, 4x4 microtile. org(m) = m/1536; 1536%64==0 so
// a row-block never straddles orgs (org_ids are repeat(arange(3),1536) in this input).
// ---------------------------------------------------------------------------
template<bool TANH>
__global__ __launch_bounds__(256) void gemm_kern(
    const float* __restrict__ S, const float* __restrict__ W,
    const float* __restrict__ bias, float* __restrict__ out,
    int K, int Nn)
{
  __shared__ float sS[16][64];   // [k][m]
  __shared__ float sW[16][64];   // [k][n]
  const int t  = threadIdx.x;
  const int tx = t & 15, ty = t >> 4;
  const int m0 = blockIdx.y * 64, n0 = blockIdx.x * 64;
  const int org = m0 / NPO;
  const float* __restrict__ Wk = W + (size_t)org * K * Nn;

  const int ls_m = t >> 2;          // 0..63
  const int ls_k = (t & 3) << 2;    // 0,4,8,12
  const int lw_n = (t & 15) << 2;   // 0..60
  const int lw_k = t >> 4;          // 0..15

  float acc[4][4] = {};

  for (int kc = 0; kc < K; kc += 16) {
    float4 sv = *(const float4*)(S  + (size_t)(m0 + ls_m) * K  + kc + ls_k);
    float4 wv = *(const float4*)(Wk + (size_t)(kc + lw_k) * Nn + n0 + lw_n);
    __syncthreads();
    sS[ls_k + 0][ls_m] = sv.x;
    sS[ls_k + 1][ls_m] = sv.y;
    sS[ls_k + 2][ls_m] = sv.z;
    sS[ls_k + 3][ls_m] = sv.w;
    *(float4*)&sW[lw_k][lw_n] = wv;
    __syncthreads();
#pragma unroll
    for (int kk = 0; kk < 16; ++kk) {
      float4 bv = *(const float4*)&sW[kk][tx << 2];
      float4 av = *(const float4*)&sS[kk][ty << 2];
      acc[0][0] += av.x * bv.x; acc[0][1] += av.x * bv.y; acc[0][2] += av.x * bv.z; acc[0][3] += av.x * bv.w;
      acc[1][0] += av.y * bv.x; acc[1][1] += av.y * bv.y; acc[1][2] += av.y * bv.z; acc[1][3] += av.y * bv.w;
      acc[2][0] += av.z * bv.x; acc[2][1] += av.z * bv.y; acc[2][2] += av.z * bv.z; acc[2][3] += av.z * bv.w;
      acc[3][0] += av.w * bv.x; acc[3][1] += av.w * bv.y; acc[3][2] += av.w * bv.z; acc[3][3] += av.w * bv.w;
    }
  }
#pragma unroll
  for (int i2 = 0; i2 < 4; ++i2) {
    int row = m0 + (ty << 2) + i2;
    int col = n0 + (tx << 2);
    float4 bb = *(const float4*)(bias + (size_t)org * Nn + col);
    float4 o;
    o.x = acc[i2][0] + bb.x;
    o.y = acc[i2][1] + bb.y;
    o.z = acc[i2][2] + bb.z;
    o.w = acc[i2][3] + bb.w;
    if (TANH) { o.x = tanhf(o.x); o.y = tanhf(o.y); o.z = tanhf(o.z); o.w = tanhf(o.w); }
    *(float4*)(out + (size_t)row * Nn + col) = o;
  }
}

// ---------------------------------------------------------------------------
// Per-agent kernel: one block (256 threads) per agent.
// Phase 1: scan all N agents -> neighbor counts + same-org neighbor list.
// Phase 2: dot(a_i, sum_nb b_j) and dot(b_i, sum_nb a_j) over h-slices.
// Phase 3: epilogue (states update, energy, roles, output row).
// Deterministic: integer atomics only; neighbor list sorted by thread 0;
// float reduction in fixed order (wave shuffle -> 4 partials -> thread 0).
// ---------------------------------------------------------------------------
__global__ __launch_bounds__(256) void agent_kernel(
    const float* __restrict__ states, const float* __restrict__ energies,
    const float* __restrict__ resource_grid,
    const int* __restrict__ roles, const int* __restrict__ org_ids,
    const int* __restrict__ positions,
    const float* __restrict__ A, const float* __restrict__ Bm,
    const float* __restrict__ SP, float* __restrict__ out)
{
  const int i = blockIdx.x;
  const int t = threadIdx.x;

  __shared__ int nb_list[NPO];
  __shared__ int s_cnt, s_mass, s_fi, s_enemy, s_nbn;
  __shared__ float wpo[4], wpi[4];

  if (t == 0) { s_cnt = 0; s_mass = 0; s_fi = 0; s_enemy = 0; s_nbn = 0; }
  __syncthreads();

  const int2 pi_pos = ((const int2*)positions)[i];
  const int  my_org = org_ids[i];

  int c_cnt = 0, c_mass = 0, c_fi = 0, c_enemy = 0;
  for (int j = t; j < N_AG; j += 256) {
    int2 pj = ((const int2*)positions)[j];
    int dx = pj.x - pi_pos.x, dy = pj.y - pi_pos.y;
    if (dx * dx + dy * dy > 25 || j == i) continue;
    int oj = org_ids[j];
    int rj = roles[j];
    if (oj == my_org) {
      c_cnt++;
      if (rj == 0) c_mass++;
      if (rj == 1) c_fi++;
      int slot = atomicAdd(&s_nbn, 1);
      nb_list[slot] = j;
    } else {
      if (rj == 1) c_enemy++;
    }
  }
  if (c_cnt)   atomicAdd(&s_cnt, c_cnt);
  if (c_mass)  atomicAdd(&s_mass, c_mass);
  if (c_fi)    atomicAdd(&s_fi, c_fi);
  if (c_enemy) atomicAdd(&s_enemy, c_enemy);
  __syncthreads();

  // canonical (sorted) neighbor order for deterministic float accumulation
  if (t == 0) {
    int n = s_nbn;
    for (int a = 1; a < n; ++a) {
      int v = nb_list[a];
      int b = a - 1;
      while (b >= 0 && nb_list[b] > v) { nb_list[b + 1] = nb_list[b]; --b; }
      nb_list[b + 1] = v;
    }
  }
  __syncthreads();

  const int nbn  = s_nbn;
  const int cnt  = s_cnt, mass = s_mass, fi = s_fi, enemy = s_enemy;
  const bool has_nb = cnt > 0;

  // phase 2: dots. thread t owns h = t and h = t+256.
  float a0 = A [(size_t)i * H_DIM + t], a1 = A [(size_t)i * H_DIM + 256 + t];
  float b0 = Bm[(size_t)i * H_DIM + t], b1 = Bm[(size_t)i * H_DIM + 256 + t];
  float po = 0.f, pin = 0.f;
  for (int s = 0; s < nbn; ++s) {
    int j = nb_list[s];
    po  += a0 * Bm[(size_t)j * H_DIM + t] + a1 * Bm[(size_t)j * H_DIM + 256 + t];
    pin += b0 * A [(size_t)j * H_DIM + t] + b1 * A [(size_t)j * H_DIM + 256 + t];
  }
#pragma unroll
  for (int off = 32; off; off >>= 1) {
    po  += __shfl_down(po, off, 64);
    pin += __shfl_down(pin, off, 64);
  }
  if ((t & 63) == 0) { wpo[t >> 6] = po; wpi[t >> 6] = pin; }
  __syncthreads();

  // phase 3: outputs
  float st = states[(size_t)i * D_DIM + t];
  float ns = has_nb ? st + 0.1f * SP[(size_t)i * D_DIM + t] : st;
  out[(size_t)i * 261 + t] = ns;

  if (t == 0) {
    float po_t = wpo[0] + wpo[1] + wpo[2] + wpo[3];
    float pi_t = wpi[0] + wpi[1] + wpi[2] + wpi[3];
    float denom = fmaxf((float)cnt, 1.0f);
    const float invs = 0.044194173824159216f;  // 1/sqrt(512)
    float out_mean = po_t * invs / denom;
    float in_mean  = pi_t * invs / denom;
    float ni = has_nb ? (out_mean - in_mean) : 0.f;

    float res = resource_grid[pi_pos.y * GRID_SZ + pi_pos.x];
    float e = energies[i];
    int   r = roles[i];
    float e_fi   = e + 0.03f * (float)mass + 0.02f * res - 0.04f * (float)enemy - 0.01f;
    float e_mass = e * 0.98f + 0.02f * ((fi > 0) ? 1.f : 0.f) + 0.01f * res - 0.02f * (float)enemy;
    float ne = (r == 1) ? e_fi : e_mass;
    ne = fminf(fmaxf(ne, 0.f), 1.f);
    bool can_fi = (ne > 0.5f) && (mass >= 2) && (fi == 0) && (enemy == 0);
    int r0n = can_fi ? 1 : 0;
    bool loses = (mass < 1) || (ne < 0.15f) || (enemy > fi + 1);
    int r1n = loses ? 0 : 1;
    int nr = (r == 0) ? r0n : ((r == 1) ? r1n : r);

    float* orow = out + (size_t)i * 261;
    orow[256] = ni;
    orow[257] = ne;
    orow[258] = (nr == 0) ? 1.f : 0.f;
    orow[259] = (nr == 1) ? 1.f : 0.f;
    orow[260] = (nr == 2) ? 1.f : 0.f;
  }
}

extern "C" void kernel_launch(void* const* d_in, const int* in_sizes, int n_in,
                              void* d_out, int out_size, void* d_ws, size_t ws_size,
                              hipStream_t stream) {
  const float* states        = (const float*)d_in[0];
  const float* energies      = (const float*)d_in[1];
  const float* resource_grid = (const float*)d_in[2];
  const float* W_out         = (const float*)d_in[3];
  const float* b_out         = (const float*)d_in[4];
  const float* W_in          = (const float*)d_in[5];
  const float* b_in          = (const float*)d_in[6];
  const float* W1            = (const float*)d_in[7];
  const float* b1            = (const float*)d_in[8];
  const float* W2            = (const float*)d_in[9];
  const float* b2            = (const float*)d_in[10];
  const int*   roles         = (const int*)d_in[11];
  const int*   org_ids       = (const int*)d_in[12];
  const int*   positions     = (const int*)d_in[13];
  float*       out           = (float*)d_out;

  float* A  = (float*)d_ws;                 // N x H
  float* Bm = A  + (size_t)N_AG * H_DIM;    // N x H
  float* H1 = Bm + (size_t)N_AG * H_DIM;    // N x H
  float* SP = H1 + (size_t)N_AG * H_DIM;    // N x D
  // total: 3*N*H + N*D floats = 31.5 MiB of d_ws

  dim3 blk(256);
  dim3 g1(H_DIM / 64, N_AG / 64);
  gemm_kern<true><<<g1, blk, 0, stream>>>(states, W_out, b_out, A,  D_DIM, H_DIM);
  gemm_kern<true><<<g1, blk, 0, stream>>>(states, W_in,  b_in,  Bm, D_DIM, H_DIM);
  gemm_kern<true><<<g1, blk, 0, stream>>>(states, W1,    b1,    H1, D_DIM, H_DIM);
  dim3 g2(D_DIM / 64, N_AG / 64);
  gemm_kern<false><<<g2, blk, 0, stream>>>(H1, W2, b2, SP, H_DIM, D_DIM);
  agent_kernel<<<dim3(N_AG), blk, 0, stream>>>(states, energies, resource_grid,
                                               roles, org_ids, positions,
                                               A, Bm, SP, out);
}

// Round 2
// 61.472 us; speedup vs baseline: 2.5569x; 2.5569x over previous
//
#include <hip/hip_runtime.h>

#define M_AG   4608
#define NPO    1536
#define D_DIM  256
#define H_DIM  512
#define NBIG   1536
#define GRID_SZ 256

typedef __attribute__((ext_vector_type(8))) short short8;
typedef __attribute__((ext_vector_type(4))) float f32x4;
typedef unsigned short ushort_t;

__device__ __forceinline__ ushort_t f2bf(float f) {
  unsigned int u = __builtin_bit_cast(unsigned int, f);
  unsigned int r = (u + 0x7FFFu + ((u >> 16) & 1u)) >> 16;   // RNE, finite inputs
  return (ushort_t)r;
}
__device__ __forceinline__ float bf2f(ushort_t u) {
  return __builtin_bit_cast(float, (unsigned int)u << 16);
}

// ---------------------------------------------------------------------------
// Pack kernels: fp32 -> bf16 k-chunked layouts.
// Sc layout:  [256/8][M][8]   element (m,k) at ((k>>3)*M + m)*8 + (k&7)
// Wc layout:  [org][256/8][1536][8]  (n-concat of W_out|W_in|W1)
// W2c layout: [org][512/8][256][8]
// ---------------------------------------------------------------------------
__global__ __launch_bounds__(256) void pack_S(const float* __restrict__ S,
                                              ushort_t* __restrict__ Sc) {
  int idx = blockIdx.x * 256 + threadIdx.x;           // < 32*4608
  int kc = idx / M_AG;
  int m  = idx - kc * M_AG;
  const float* p = S + (size_t)m * D_DIM + kc * 8;
  ushort_t* d = Sc + (size_t)idx * 8;
#pragma unroll
  for (int j = 0; j < 8; ++j) d[j] = f2bf(p[j]);
}

__global__ __launch_bounds__(256) void pack_W(const float* __restrict__ W_out,
                                              const float* __restrict__ W_in,
                                              const float* __restrict__ W1,
                                              ushort_t* __restrict__ Wc) {
  int idx = blockIdx.x * 256 + threadIdx.x;           // < 3*32*1536
  int org = idx / (32 * NBIG);
  int rem = idx - org * (32 * NBIG);
  int kc = rem / NBIG;
  int n  = rem - kc * NBIG;
  int which = n >> 9, nl = n & 511;
  const float* Wsel = (which == 0 ? W_out : which == 1 ? W_in : W1);
  const float* p = Wsel + (size_t)org * (D_DIM * H_DIM) + (size_t)kc * 8 * H_DIM + nl;
  ushort_t* d = Wc + (size_t)idx * 8;
#pragma unroll
  for (int j = 0; j < 8; ++j) d[j] = f2bf(p[(size_t)j * H_DIM]);
}

__global__ __launch_bounds__(256) void pack_W2(const float* __restrict__ W2,
                                               ushort_t* __restrict__ W2c) {
  int idx = blockIdx.x * 256 + threadIdx.x;           // < 3*64*256
  int org = idx / (64 * D_DIM);
  int rem = idx - org * (64 * D_DIM);
  int kc = rem >> 8;
  int n  = rem & 255;
  const float* p = W2 + (size_t)org * (H_DIM * D_DIM) + (size_t)kc * 8 * D_DIM + n;
  ushort_t* d = W2c + (size_t)idx * 8;
#pragma unroll
  for (int j = 0; j < 8; ++j) d[j] = f2bf(p[(size_t)j * D_DIM]);
}

// ---------------------------------------------------------------------------
// Fused bf16 MFMA GEMM: [A|B|H1] = tanh(S*[W_out|W_in|W1] + bias)
// tile 64x64, BK=32, 4 waves, wave = 32x32 (2x2 fragments of 16x16x32).
// LDS fragment layout [kgroup g][row][8 bf16]: staging write = t-linear 16B
// (conflict-free), frag ds_read_b128 = consecutive lanes consecutive 16B
// (conflict-free). k-permutation identical for A and B operands -> cancels.
// ---------------------------------------------------------------------------
__global__ __launch_bounds__(256) void gemm_fused(
    const ushort_t* __restrict__ Sc, const ushort_t* __restrict__ Wc,
    const float* __restrict__ b_out, const float* __restrict__ b_in,
    const float* __restrict__ b1,
    ushort_t* __restrict__ Abf, ushort_t* __restrict__ Bbf,
    ushort_t* __restrict__ Hc)
{
  __shared__ ushort_t Asm[2048], Bsm[2048];
  const int t = threadIdx.x;
  const int g = t >> 6, mm = t & 63;         // staging role
  const int w = t >> 6, l = t & 63;
  const int wm = w >> 1, wn = w & 1;
  const int lr = l & 15, lg = l >> 4;
  const int n0 = blockIdx.x * 64;            // 0..1535
  const int m0 = blockIdx.y * 64;
  const int org = m0 / NPO;

  f32x4 acc[2][2] = {};
  const short8* Ap = (const short8*)Asm;
  const short8* Bp = (const short8*)Bsm;

  for (int kc8 = 0; kc8 < 32; kc8 += 4) {
    short8 va = *(const short8*)(Sc + ((size_t)(kc8 + g) * M_AG + m0 + mm) * 8);
    short8 vb = *(const short8*)(Wc + ((size_t)(org * 32 + kc8 + g) * NBIG + n0 + mm) * 8);
    __syncthreads();
    *(short8*)(Asm + t * 8) = va;
    *(short8*)(Bsm + t * 8) = vb;
    __syncthreads();
    short8 a0  = Ap[lg * 64 + wm * 32 + lr];
    short8 a1  = Ap[lg * 64 + wm * 32 + 16 + lr];
    short8 bq0 = Bp[lg * 64 + wn * 32 + lr];
    short8 bq1 = Bp[lg * 64 + wn * 32 + 16 + lr];
    acc[0][0] = __builtin_amdgcn_mfma_f32_16x16x32_bf16(a0, bq0, acc[0][0], 0, 0, 0);
    acc[0][1] = __builtin_amdgcn_mfma_f32_16x16x32_bf16(a0, bq1, acc[0][1], 0, 0, 0);
    acc[1][0] = __builtin_amdgcn_mfma_f32_16x16x32_bf16(a1, bq0, acc[1][0], 0, 0, 0);
    acc[1][1] = __builtin_amdgcn_mfma_f32_16x16x32_bf16(a1, bq1, acc[1][1], 0, 0, 0);
  }

  const int which = n0 >> 9;
  const int nlb = n0 & 511;
  const float* bias = (which == 0 ? b_out : which == 1 ? b_in : b1) + org * H_DIM;
  ushort_t* dst01 = (which == 0) ? Abf : Bbf;
#pragma unroll
  for (int mi = 0; mi < 2; ++mi)
#pragma unroll
    for (int ni = 0; ni < 2; ++ni) {
      int nl = nlb + wn * 32 + ni * 16 + lr;
      float bb = bias[nl];
#pragma unroll
      for (int r = 0; r < 4; ++r) {
        int row = m0 + wm * 32 + mi * 16 + lg * 4 + r;
        ushort_t hv = f2bf(tanhf(acc[mi][ni][r] + bb));
        if (which < 2) dst01[(size_t)row * H_DIM + nl] = hv;
        else           Hc[((size_t)(nl >> 3) * M_AG + row) * 8 + (nl & 7)] = hv;
      }
    }
}

// SP = H1*W2 + b2  (M=4608, K=512, N=256), fp32 out, no activation
__global__ __launch_bounds__(256) void gemm_sp(
    const ushort_t* __restrict__ Hc, const ushort_t* __restrict__ W2c,
    const float* __restrict__ b2, float* __restrict__ SP)
{
  __shared__ ushort_t Asm[2048], Bsm[2048];
  const int t = threadIdx.x;
  const int g = t >> 6, mm = t & 63;
  const int w = t >> 6, l = t & 63;
  const int wm = w >> 1, wn = w & 1;
  const int lr = l & 15, lg = l >> 4;
  const int n0 = blockIdx.x * 64;            // 0..255
  const int m0 = blockIdx.y * 64;
  const int org = m0 / NPO;

  f32x4 acc[2][2] = {};
  const short8* Ap = (const short8*)Asm;
  const short8* Bp = (const short8*)Bsm;

  for (int kc8 = 0; kc8 < 64; kc8 += 4) {
    short8 va = *(const short8*)(Hc  + ((size_t)(kc8 + g) * M_AG + m0 + mm) * 8);
    short8 vb = *(const short8*)(W2c + ((size_t)(org * 64 + kc8 + g) * D_DIM + n0 + mm) * 8);
    __syncthreads();
    *(short8*)(Asm + t * 8) = va;
    *(short8*)(Bsm + t * 8) = vb;
    __syncthreads();
    short8 a0  = Ap[lg * 64 + wm * 32 + lr];
    short8 a1  = Ap[lg * 64 + wm * 32 + 16 + lr];
    short8 bq0 = Bp[lg * 64 + wn * 32 + lr];
    short8 bq1 = Bp[lg * 64 + wn * 32 + 16 + lr];
    acc[0][0] = __builtin_amdgcn_mfma_f32_16x16x32_bf16(a0, bq0, acc[0][0], 0, 0, 0);
    acc[0][1] = __builtin_amdgcn_mfma_f32_16x16x32_bf16(a0, bq1, acc[0][1], 0, 0, 0);
    acc[1][0] = __builtin_amdgcn_mfma_f32_16x16x32_bf16(a1, bq0, acc[1][0], 0, 0, 0);
    acc[1][1] = __builtin_amdgcn_mfma_f32_16x16x32_bf16(a1, bq1, acc[1][1], 0, 0, 0);
  }

#pragma unroll
  for (int mi = 0; mi < 2; ++mi)
#pragma unroll
    for (int ni = 0; ni < 2; ++ni) {
      int nl = n0 + wn * 32 + ni * 16 + lr;
      float bb = b2[org * D_DIM + nl];
#pragma unroll
      for (int r = 0; r < 4; ++r) {
        int row = m0 + wm * 32 + mi * 16 + lg * 4 + r;
        SP[(size_t)row * D_DIM + nl] = acc[mi][ni][r] + bb;
      }
    }
}

// ---------------------------------------------------------------------------
// Per-agent kernel (one 256-thread block per agent). A/B now bf16.
// ---------------------------------------------------------------------------
__global__ __launch_bounds__(256) void agent_kernel(
    const float* __restrict__ states, const float* __restrict__ energies,
    const float* __restrict__ resource_grid,
    const int* __restrict__ roles, const int* __restrict__ org_ids,
    const int* __restrict__ positions,
    const ushort_t* __restrict__ A, const ushort_t* __restrict__ Bm,
    const float* __restrict__ SP, float* __restrict__ out)
{
  const int i = blockIdx.x;
  const int t = threadIdx.x;

  __shared__ int nb_list[NPO];
  __shared__ int s_cnt, s_mass, s_fi, s_enemy, s_nbn;
  __shared__ float wpo[4], wpi[4];

  if (t == 0) { s_cnt = 0; s_mass = 0; s_fi = 0; s_enemy = 0; s_nbn = 0; }
  __syncthreads();

  const int2 pi_pos = ((const int2*)positions)[i];
  const int  my_org = org_ids[i];

  int c_cnt = 0, c_mass = 0, c_fi = 0, c_enemy = 0;
  for (int j = t; j < M_AG; j += 256) {
    int2 pj = ((const int2*)positions)[j];
    int dx = pj.x - pi_pos.x, dy = pj.y - pi_pos.y;
    if (dx * dx + dy * dy > 25 || j == i) continue;
    int oj = org_ids[j];
    int rj = roles[j];
    if (oj == my_org) {
      c_cnt++;
      if (rj == 0) c_mass++;
      if (rj == 1) c_fi++;
      int slot = atomicAdd(&s_nbn, 1);
      nb_list[slot] = j;
    } else {
      if (rj == 1) c_enemy++;
    }
  }
  if (c_cnt)   atomicAdd(&s_cnt, c_cnt);
  if (c_mass)  atomicAdd(&s_mass, c_mass);
  if (c_fi)    atomicAdd(&s_fi, c_fi);
  if (c_enemy) atomicAdd(&s_enemy, c_enemy);
  __syncthreads();

  if (t == 0) {  // canonical order -> deterministic float accumulation
    int n = s_nbn;
    for (int a = 1; a < n; ++a) {
      int v = nb_list[a];
      int b = a - 1;
      while (b >= 0 && nb_list[b] > v) { nb_list[b + 1] = nb_list[b]; --b; }
      nb_list[b + 1] = v;
    }
  }
  __syncthreads();

  const int nbn = s_nbn;
  const int cnt = s_cnt, mass = s_mass, fi = s_fi, enemy = s_enemy;
  const bool has_nb = cnt > 0;

  float a0 = bf2f(A [(size_t)i * H_DIM + t]), a1 = bf2f(A [(size_t)i * H_DIM + 256 + t]);
  float b0 = bf2f(Bm[(size_t)i * H_DIM + t]), b1 = bf2f(Bm[(size_t)i * H_DIM + 256 + t]);
  float po = 0.f, pin = 0.f;
  for (int s = 0; s < nbn; ++s) {
    int j = nb_list[s];
    po  += a0 * bf2f(Bm[(size_t)j * H_DIM + t]) + a1 * bf2f(Bm[(size_t)j * H_DIM + 256 + t]);
    pin += b0 * bf2f(A [(size_t)j * H_DIM + t]) + b1 * bf2f(A [(size_t)j * H_DIM + 256 + t]);
  }
#pragma unroll
  for (int off = 32; off; off >>= 1) {
    po  += __shfl_down(po, off, 64);
    pin += __shfl_down(pin, off, 64);
  }
  if ((t & 63) == 0) { wpo[t >> 6] = po; wpi[t >> 6] = pin; }
  __syncthreads();

  float st = states[(size_t)i * D_DIM + t];
  float ns = has_nb ? st + 0.1f * SP[(size_t)i * D_DIM + t] : st;
  out[(size_t)i * 261 + t] = ns;

  if (t == 0) {
    float po_t = wpo[0] + wpo[1] + wpo[2] + wpo[3];
    float pi_t = wpi[0] + wpi[1] + wpi[2] + wpi[3];
    float denom = fmaxf((float)cnt, 1.0f);
    const float invs = 0.044194173824159216f;  // 1/sqrt(512)
    float ni = has_nb ? (po_t - pi_t) * invs / denom : 0.f;

    float res = resource_grid[pi_pos.y * GRID_SZ + pi_pos.x];
    float e = energies[i];
    int   r = roles[i];
    float e_fi   = e + 0.03f * (float)mass + 0.02f * res - 0.04f * (float)enemy - 0.01f;
    float e_mass = e * 0.98f + 0.02f * ((fi > 0) ? 1.f : 0.f) + 0.01f * res - 0.02f * (float)enemy;
    float ne = (r == 1) ? e_fi : e_mass;
    ne = fminf(fmaxf(ne, 0.f), 1.f);
    bool can_fi = (ne > 0.5f) && (mass >= 2) && (fi == 0) && (enemy == 0);
    int r0n = can_fi ? 1 : 0;
    bool loses = (mass < 1) || (ne < 0.15f) || (enemy > fi + 1);
    int r1n = loses ? 0 : 1;
    int nr = (r == 0) ? r0n : ((r == 1) ? r1n : r);

    float* orow = out + (size_t)i * 261;
    orow[256] = ni;
    orow[257] = ne;
    orow[258] = (nr == 0) ? 1.f : 0.f;
    orow[259] = (nr == 1) ? 1.f : 0.f;
    orow[260] = (nr == 2) ? 1.f : 0.f;
  }
}

extern "C" void kernel_launch(void* const* d_in, const int* in_sizes, int n_in,
                              void* d_out, int out_size, void* d_ws, size_t ws_size,
                              hipStream_t stream) {
  const float* states        = (const float*)d_in[0];
  const float* energies      = (const float*)d_in[1];
  const float* resource_grid = (const float*)d_in[2];
  const float* W_out         = (const float*)d_in[3];
  const float* b_out         = (const float*)d_in[4];
  const float* W_in          = (const float*)d_in[5];
  const float* b_in          = (const float*)d_in[6];
  const float* W1            = (const float*)d_in[7];
  const float* b1            = (const float*)d_in[8];
  const float* W2            = (const float*)d_in[9];
  const float* b2            = (const float*)d_in[10];
  const int*   roles         = (const int*)d_in[11];
  const int*   org_ids       = (const int*)d_in[12];
  const int*   positions     = (const int*)d_in[13];
  float*       out           = (float*)d_out;

  char* ws = (char*)d_ws;
  ushort_t* Sc  = (ushort_t*)(ws);              //  2,359,296 B  [32][4608][8]
  ushort_t* Wc  = (ushort_t*)(ws +  2359296);   //  2,359,296 B  [3][32][1536][8]
  ushort_t* W2c = (ushort_t*)(ws +  4718592);   //    786,432 B  [3][64][256][8]
  ushort_t* Hc  = (ushort_t*)(ws +  5505024);   //  4,718,592 B  [64][4608][8]
  ushort_t* Abf = (ushort_t*)(ws + 10223616);   //  4,718,592 B  [4608][512]
  ushort_t* Bbf = (ushort_t*)(ws + 14942208);   //  4,718,592 B  [4608][512]
  float*    SP  = (float*)   (ws + 19660800);   //  4,718,592 B  [4608][256]
  // total 24,379,392 B of d_ws (round 1 used 31.5 MB successfully)

  pack_S <<<576, 256, 0, stream>>>(states, Sc);
  pack_W <<<576, 256, 0, stream>>>(W_out, W_in, W1, Wc);
  pack_W2<<<192, 256, 0, stream>>>(W2, W2c);
  gemm_fused<<<dim3(24, 72), 256, 0, stream>>>(Sc, Wc, b_out, b_in, b1, Abf, Bbf, Hc);
  gemm_sp   <<<dim3(4, 72),  256, 0, stream>>>(Hc, W2c, b2, SP);
  agent_kernel<<<4608, 256, 0, stream>>>(states, energies, resource_grid,
                                         roles, org_ids, positions,
                                         Abf, Bbf, SP, out);
}